// Round 6
// baseline (127.587 us; speedup 1.0000x reference)
//
#include <hip/hip_runtime.h>
#include <hip/hip_bf16.h>

#define CH   128
#define HH   64
#define WW   64
#define OFFC 18

typedef __attribute__((ext_vector_type(8))) short bf16x8;
typedef __attribute__((ext_vector_type(4))) short bf16x4;
typedef __attribute__((ext_vector_type(4))) float f32x4;

static __device__ __forceinline__ unsigned short f2bf(float f) {
    __hip_bfloat16 h = __float2bfloat16(f);
    return *reinterpret_cast<unsigned short*>(&h);
}
static __device__ __forceinline__ float bf2f(unsigned short u) {
    union { unsigned int i; float f; } x; x.i = ((unsigned int)u) << 16;
    return x.f;
}

// ---------------------------------------------------------------------------
// Prep: pack all four weight tensors to bf16 MFMA A-fragment order AND
// convert x NCHW f32 -> NHWC bf16, one launch.
// blocks 0..575    : wdc1 -> wpk1   [((k*4+kk)*8+ot)*512 + lane*8 + j]
// blocks 576..1151 : wdc2 -> wpk2
// blocks 1152..1295: wof1 -> wpo1   [((k*4+kk)*2+mt)*512 + lane*8 + j], co pad 32
// blocks 1296..1439: wof2 -> wpo2
// blocks 1440..1951: x -> xh (one block per (b,h) row)
// ---------------------------------------------------------------------------
__global__ __launch_bounds__(256) void prep_kernel(
    const float* __restrict__ x, unsigned short* __restrict__ xh,
    const float* __restrict__ wdc1, const float* __restrict__ wdc2,
    const float* __restrict__ wof1, const float* __restrict__ wof2,
    unsigned short* __restrict__ wpk1, unsigned short* __restrict__ wpk2,
    unsigned short* __restrict__ wpo1, unsigned short* __restrict__ wpo2)
{
    __shared__ float s[CH][WW + 1];
    int blk = blockIdx.x;
    int tid = threadIdx.x;

    if (blk < 1152) {
        const float* w = (blk < 576) ? wdc1 : wdc2;
        unsigned short* wp = (blk < 576) ? wpk1 : wpk2;
        int id = (blk % 576) * 256 + tid;          // 0..147455
        int j    = id & 7;
        int lane = (id >> 3) & 63;
        int ot   = (id >> 9) & 7;
        int kk   = (id >> 12) & 3;
        int k    = id >> 14;
        int o = ot * 16 + (lane & 15);
        int i = kk * 32 + (lane >> 4) * 8 + j;
        wp[id] = f2bf(w[(o * CH + i) * 9 + k]);
        return;
    }
    if (blk < 1440) {
        const float* w = (blk < 1296) ? wof1 : wof2;
        unsigned short* wp = (blk < 1296) ? wpo1 : wpo2;
        int id = ((blk - 1152) % 144) * 256 + tid; // 0..36863
        int j    = id & 7;
        int lane = (id >> 3) & 63;
        int mt   = (id >> 9) & 1;
        int kk   = (id >> 10) & 3;
        int k    = id >> 12;
        int o = mt * 16 + (lane & 15);
        int i = kk * 32 + (lane >> 4) * 8 + j;
        wp[id] = (o < OFFC) ? f2bf(w[(o * CH + i) * 9 + k]) : (unsigned short)0;
        return;
    }

    // ---- NCHW f32 -> NHWC bf16 ----------------------------------------
    int nb = blk - 1440;                     // b*64 + h
    const float* xb = x + ((size_t)(nb >> 6) * CH * HH + (nb & 63)) * WW;

    int c_off = tid >> 4, w0 = (tid & 15) * 4;
    #pragma unroll
    for (int it = 0; it < 8; ++it) {
        int c = it * 16 + c_off;
        float4 vv = *(const float4*)&xb[(size_t)c * HH * WW + w0];
        s[c][w0] = vv.x; s[c][w0 + 1] = vv.y; s[c][w0 + 2] = vv.z; s[c][w0 + 3] = vv.w;
    }
    __syncthreads();

    int w = tid & 63, c0 = (tid >> 6) * 32;
    unsigned short* dst = xh + ((size_t)nb * WW + w) * CH + c0;
    unsigned short tmp[32];
    #pragma unroll
    for (int j = 0; j < 32; ++j) tmp[j] = f2bf(s[c0 + j][w]);
    #pragma unroll
    for (int q = 0; q < 4; ++q)
        *(bf16x8*)(dst + q * 8) = *(const bf16x8*)(tmp + q * 8);
}

// ---------------------------------------------------------------------------
// FUSED: offset-conv (3x3 s1 p1, Co=18 pad 32) + deformable conv
// (K=3, s1, pad 2, dil 2) + BN (+residual) + ReLU, all via bf16 MFMA.
// Block = (b, oh) [XCD-swizzled by b], 512 blocks x 256 thr (4 waves), N=64.
// Phase 0: offset patch 18x64 -> off_lds (f32) via MFMA on xh rows oh-1..oh+1.
// Main loop per tap: sample 128ci x 64ow -> swizzled bf16 sB; 32 MFMA/wave.
// ---------------------------------------------------------------------------
__global__ __launch_bounds__(256) void deform_fused_kernel(
    const unsigned short* __restrict__ xh,    // (B,64,64,128) bf16 input
    const unsigned short* __restrict__ wpo,   // packed offset-conv A frags
    const float* __restrict__ bias,           // (18)
    const unsigned short* __restrict__ wpk,   // packed deform A frags
    const float* __restrict__ g, const float* __restrict__ beta,
    const float* __restrict__ m, const float* __restrict__ v,
    const float* __restrict__ residual,       // layer2 only
    unsigned short* __restrict__ out_h,       // layer1: NHWC bf16 out
    float* __restrict__ out_f)                // layer2: NCHW f32 out
{
    __shared__ unsigned short sB[64 * 128];   // 16 KB [ow][ci], swizzled
    __shared__ float off_lds[OFFC][WW];       // 4.5 KB offset patch (f32)

    int wgid = blockIdx.x;                    // 512
    int blk  = (wgid & 7) * 64 + (wgid >> 3); // XCD n owns batch n
    int b = blk >> 6, oh = blk & 63;
    int tid = threadIdx.x, lane = tid & 63, wv = tid >> 6;

    const unsigned short* xb = xh + (size_t)b * HH * WW * CH;

    // ---- phase 0: offset conv for this row (wave wv = ow-tile wv) ------
    {
        f32x4 oacc0 = {0.f, 0.f, 0.f, 0.f}, oacc1 = {0.f, 0.f, 0.f, 0.f};
        for (int k = 0; k < 9; ++k) {
            int ky = k / 3, kx = k - ky * 3;
            int ih = oh - 1 + ky;
            if (ih < 0 || ih >= HH) continue;
            int iw = wv * 16 + (lane & 15) + kx - 1;
            bool valid = (iw >= 0) && (iw < WW);
            const unsigned short* row =
                xb + ((size_t)ih * WW + (valid ? iw : 0)) * CH + (lane >> 4) * 8;
            const unsigned short* wk = wpo + (size_t)k * 4096;
            #pragma unroll
            for (int kk = 0; kk < 4; ++kk) {
                bf16x8 bfrag = {0, 0, 0, 0, 0, 0, 0, 0};
                if (valid) bfrag = *(const bf16x8*)(row + kk * 32);
                bf16x8 a0 = *(const bf16x8*)(wk + (kk * 2 + 0) * 512 + lane * 8);
                bf16x8 a1 = *(const bf16x8*)(wk + (kk * 2 + 1) * 512 + lane * 8);
                oacc0 = __builtin_amdgcn_mfma_f32_16x16x32_bf16(a0, bfrag, oacc0, 0, 0, 0);
                oacc1 = __builtin_amdgcn_mfma_f32_16x16x32_bf16(a1, bfrag, oacc1, 0, 0, 0);
            }
        }
        int ow = wv * 16 + (lane & 15);
        #pragma unroll
        for (int r = 0; r < 4; ++r) {
            int co = (lane >> 4) * 4 + r;                 // 0..15
            off_lds[co][ow] = oacc0[r] + bias[co];
        }
        if ((lane >> 4) == 0) {
            #pragma unroll
            for (int r = 0; r < 2; ++r) {
                int co = 16 + r;                          // 16,17
                off_lds[co][ow] = oacc1[r] + bias[co];
            }
        }
    }
    __syncthreads();

    // ---- main deform loop ---------------------------------------------
    int s_ow = tid & 63;                      // sampling ow
    int ci0  = (tid >> 6) * 32;               // sampling ci block (32)

    f32x4 acc[2][4];                          // [o-tile local][ow-tile]
    #pragma unroll
    for (int a = 0; a < 2; ++a)
        #pragma unroll
        for (int q = 0; q < 4; ++q) acc[a][q] = (f32x4){0.f, 0.f, 0.f, 0.f};

    for (int k = 0; k < 9; ++k) {
        int ky = k / 3, kx = k - ky * 3;

        // per-thread bilinear coords (offsets from LDS, f32)
        float dy = off_lds[2 * k][s_ow];
        float dx = off_lds[2 * k + 1][s_ow];
        float ys = (float)(oh - 2 + ky * 2) + dy;
        float xs = (float)(s_ow - 2 + kx * 2) + dx;
        float y0f = floorf(ys), x0f = floorf(xs);
        float fy = ys - y0f, fx = xs - x0f;
        int y0 = (int)y0f, x0i = (int)x0f;
        int y1 = y0 + 1, x1 = x0i + 1;
        bool vy0 = (y0 >= 0) & (y0 < HH), vy1 = (y1 >= 0) & (y1 < HH);
        bool vx0 = (x0i >= 0) & (x0i < WW), vx1 = (x1 >= 0) & (x1 < WW);
        int y0c = min(max(y0, 0), HH - 1), y1c = min(max(y1, 0), HH - 1);
        int x0c = min(max(x0i, 0), WW - 1), x1c = min(max(x1, 0), WW - 1);
        float cw0 = (1.f - fy) * (1.f - fx) * ((vy0 && vx0) ? 1.f : 0.f);
        float cw1 = (1.f - fy) * fx         * ((vy0 && vx1) ? 1.f : 0.f);
        float cw2 = fy * (1.f - fx)         * ((vy1 && vx0) ? 1.f : 0.f);
        float cw3 = fy * fx                 * ((vy1 && vx1) ? 1.f : 0.f);

        const unsigned short* p0 = xb + ((size_t)(y0c * WW + x0c)) * CH + ci0;
        const unsigned short* p1 = xb + ((size_t)(y0c * WW + x1c)) * CH + ci0;
        const unsigned short* p2 = xb + ((size_t)(y1c * WW + x0c)) * CH + ci0;
        const unsigned short* p3 = xb + ((size_t)(y1c * WW + x1c)) * CH + ci0;

        // 4 corners x 32 ci cooperative loads + f32 blend -> 4 bf16x8
        int base = s_ow * 256 + ci0 * 2;
        int swz  = (s_ow & 7) << 4;
        #pragma unroll
        for (int q = 0; q < 2; ++q) {
            bf16x8 v0a = *(const bf16x8*)(p0 + q * 16), v0b = *(const bf16x8*)(p0 + q * 16 + 8);
            bf16x8 v1a = *(const bf16x8*)(p1 + q * 16), v1b = *(const bf16x8*)(p1 + q * 16 + 8);
            bf16x8 v2a = *(const bf16x8*)(p2 + q * 16), v2b = *(const bf16x8*)(p2 + q * 16 + 8);
            bf16x8 v3a = *(const bf16x8*)(p3 + q * 16), v3b = *(const bf16x8*)(p3 + q * 16 + 8);
            union { bf16x8 v8; unsigned short u[8]; } wa, wb;
            #pragma unroll
            for (int j = 0; j < 8; ++j) {
                float a0 = cw0 * bf2f((unsigned short)v0a[j])
                         + cw1 * bf2f((unsigned short)v1a[j])
                         + cw2 * bf2f((unsigned short)v2a[j])
                         + cw3 * bf2f((unsigned short)v3a[j]);
                float a1 = cw0 * bf2f((unsigned short)v0b[j])
                         + cw1 * bf2f((unsigned short)v1b[j])
                         + cw2 * bf2f((unsigned short)v2b[j])
                         + cw3 * bf2f((unsigned short)v3b[j]);
                wa.u[j] = f2bf(a0); wb.u[j] = f2bf(a1);
            }
            *(bf16x8*)((char*)sB + ((base + q * 32)      ^ swz)) = wa.v8;
            *(bf16x8*)((char*)sB + ((base + q * 32 + 16) ^ swz)) = wb.v8;
        }
        __syncthreads();

        // 32 MFMA per wave: o-tiles {2wv, 2wv+1} x 4 ow-tiles x 4 kk
        const unsigned short* wk = wpk + (size_t)k * 16384;
        #pragma unroll
        for (int kk = 0; kk < 4; ++kk) {
            bf16x8 a0 = *(const bf16x8*)(wk + (kk * 8 + 2 * wv)     * 512 + lane * 8);
            bf16x8 a1 = *(const bf16x8*)(wk + (kk * 8 + 2 * wv + 1) * 512 + lane * 8);
            #pragma unroll
            for (int owt = 0; owt < 4; ++owt) {
                int owl = owt * 16 + (lane & 15);
                int rbyte = (owl * 256 + (kk * 32 + (lane >> 4) * 8) * 2)
                            ^ ((owl & 7) << 4);
                bf16x8 bfv = *(const bf16x8*)((const char*)sB + rbyte);
                acc[0][owt] = __builtin_amdgcn_mfma_f32_16x16x32_bf16(
                                  a0, bfv, acc[0][owt], 0, 0, 0);
                acc[1][owt] = __builtin_amdgcn_mfma_f32_16x16x32_bf16(
                                  a1, bfv, acc[1][owt], 0, 0, 0);
            }
        }
        __syncthreads();
    }

    // ---- epilogue ------------------------------------------------------
    if (out_h != nullptr) {
        // layer 1: BN + ReLU -> NHWC bf16
        #pragma unroll
        for (int otl = 0; otl < 2; ++otl) {
            int ob = (2 * wv + otl) * 16 + (lane >> 4) * 4;
            float inv[4], sh[4];
            #pragma unroll
            for (int r = 0; r < 4; ++r) {
                int o = ob + r;
                float iv = g[o] / sqrtf(v[o] + 1e-5f);
                inv[r] = iv; sh[r] = beta[o] - m[o] * iv;
            }
            #pragma unroll
            for (int owt = 0; owt < 4; ++owt) {
                int ow = owt * 16 + (lane & 15);
                union { bf16x4 v4; unsigned short u[4]; } pk;
                #pragma unroll
                for (int r = 0; r < 4; ++r) {
                    float val = acc[otl][owt][r] * inv[r] + sh[r];
                    pk.u[r] = f2bf(fmaxf(val, 0.f));
                }
                *(bf16x4*)(out_h + ((size_t)(b * HH + oh) * WW + ow) * CH + ob) = pk.v4;
            }
        }
    } else {
        // layer 2: BN + residual + ReLU -> NCHW f32
        #pragma unroll
        for (int otl = 0; otl < 2; ++otl) {
            #pragma unroll
            for (int r = 0; r < 4; ++r) {
                int o = (2 * wv + otl) * 16 + (lane >> 4) * 4 + r;
                float iv = g[o] / sqrtf(v[o] + 1e-5f);
                float sh = beta[o] - m[o] * iv;
                #pragma unroll
                for (int owt = 0; owt < 4; ++owt) {
                    int ow = owt * 16 + (lane & 15);
                    size_t idx = (((size_t)b * CH + o) * HH + oh) * WW + ow;
                    float val = acc[otl][owt][r] * iv + sh + residual[idx];
                    out_f[idx] = fmaxf(val, 0.f);
                }
            }
        }
    }
}

// ---------------------------------------------------------------------------
extern "C" void kernel_launch(void* const* d_in, const int* in_sizes, int n_in,
                              void* d_out, int out_size, void* d_ws, size_t ws_size,
                              hipStream_t stream)
{
    const float* x      = (const float*)d_in[0];
    const float* w_off1 = (const float*)d_in[1];
    const float* b_off1 = (const float*)d_in[2];
    const float* w_dc1  = (const float*)d_in[3];
    const float* g1     = (const float*)d_in[4];
    const float* beta1  = (const float*)d_in[5];
    const float* m1     = (const float*)d_in[6];
    const float* v1     = (const float*)d_in[7];
    const float* w_off2 = (const float*)d_in[8];
    const float* b_off2 = (const float*)d_in[9];
    const float* w_dc2  = (const float*)d_in[10];
    const float* g2     = (const float*)d_in[11];
    const float* beta2  = (const float*)d_in[12];
    const float* m2     = (const float*)d_in[13];
    const float* v2     = (const float*)d_in[14];
    float* out = (float*)d_out;

    char* ws = (char*)d_ws;
    unsigned short* xh    = (unsigned short*)ws;                  // 8,388,608 B
    unsigned short* out1h = (unsigned short*)(ws + 8388608);      // 8,388,608 B
    unsigned short* wpk1  = (unsigned short*)(ws + 16777216);     //   294,912 B
    unsigned short* wpk2  = (unsigned short*)(ws + 17072128);     //   294,912 B
    unsigned short* wpo1  = (unsigned short*)(ws + 17367040);     //    73,728 B
    unsigned short* wpo2  = (unsigned short*)(ws + 17440768);     //    73,728 B
    // total 17,514,496 B

    prep_kernel<<<1952, 256, 0, stream>>>(x, xh, w_dc1, w_dc2, w_off1, w_off2,
                                          wpk1, wpk2, wpo1, wpo2);

    // Layer 1 (fused offset conv + deform + BN + ReLU) -> NHWC bf16
    deform_fused_kernel<<<512, 256, 0, stream>>>(xh, wpo1, b_off1, wpk1,
                                                 g1, beta1, m1, v1,
                                                 nullptr, out1h, nullptr);
    // Layer 2 (fused) + residual -> NCHW f32
    deform_fused_kernel<<<512, 256, 0, stream>>>(out1h, wpo2, b_off2, wpk2,
                                                 g2, beta2, m2, v2,
                                                 x, nullptr, out);
}

// Round 7
// 96.671 us; speedup vs baseline: 1.3198x; 1.3198x over previous
//
#include <hip/hip_runtime.h>
#include <hip/hip_bf16.h>

#define CH   128
#define HH   64
#define WW   64
#define OFFC 18

typedef __attribute__((ext_vector_type(8))) short bf16x8;
typedef __attribute__((ext_vector_type(4))) short bf16x4;
typedef __attribute__((ext_vector_type(4))) float f32x4;

static __device__ __forceinline__ unsigned short f2bf(float f) {
    __hip_bfloat16 h = __float2bfloat16(f);
    return *reinterpret_cast<unsigned short*>(&h);
}
static __device__ __forceinline__ float bf2f(unsigned short u) {
    union { unsigned int i; float f; } x; x.i = ((unsigned int)u) << 16;
    return x.f;
}

// ---------------------------------------------------------------------------
// Prep: pack all four weight tensors to bf16 MFMA A-fragment order AND
// convert x NCHW f32 -> NHWC bf16, one launch.  (unchanged from round 5)
// ---------------------------------------------------------------------------
__global__ __launch_bounds__(256) void prep_kernel(
    const float* __restrict__ x, unsigned short* __restrict__ xh,
    const float* __restrict__ wdc1, const float* __restrict__ wdc2,
    const float* __restrict__ wof1, const float* __restrict__ wof2,
    unsigned short* __restrict__ wpk1, unsigned short* __restrict__ wpk2,
    unsigned short* __restrict__ wpo1, unsigned short* __restrict__ wpo2)
{
    __shared__ float s[CH][WW + 1];
    int blk = blockIdx.x;
    int tid = threadIdx.x;

    if (blk < 1152) {
        const float* w = (blk < 576) ? wdc1 : wdc2;
        unsigned short* wp = (blk < 576) ? wpk1 : wpk2;
        int id = (blk % 576) * 256 + tid;          // 0..147455
        int j    = id & 7;
        int lane = (id >> 3) & 63;
        int ot   = (id >> 9) & 7;
        int kk   = (id >> 12) & 3;
        int k    = id >> 14;
        int o = ot * 16 + (lane & 15);
        int i = kk * 32 + (lane >> 4) * 8 + j;
        wp[id] = f2bf(w[(o * CH + i) * 9 + k]);
        return;
    }
    if (blk < 1440) {
        const float* w = (blk < 1296) ? wof1 : wof2;
        unsigned short* wp = (blk < 1296) ? wpo1 : wpo2;
        int id = ((blk - 1152) % 144) * 256 + tid; // 0..36863
        int j    = id & 7;
        int lane = (id >> 3) & 63;
        int mt   = (id >> 9) & 1;
        int kk   = (id >> 10) & 3;
        int k    = id >> 12;
        int o = mt * 16 + (lane & 15);
        int i = kk * 32 + (lane >> 4) * 8 + j;
        wp[id] = (o < OFFC) ? f2bf(w[(o * CH + i) * 9 + k]) : (unsigned short)0;
        return;
    }

    // ---- NCHW f32 -> NHWC bf16 ----------------------------------------
    int nb = blk - 1440;                     // b*64 + h
    const float* xb = x + ((size_t)(nb >> 6) * CH * HH + (nb & 63)) * WW;

    int c_off = tid >> 4, w0 = (tid & 15) * 4;
    #pragma unroll
    for (int it = 0; it < 8; ++it) {
        int c = it * 16 + c_off;
        float4 vv = *(const float4*)&xb[(size_t)c * HH * WW + w0];
        s[c][w0] = vv.x; s[c][w0 + 1] = vv.y; s[c][w0 + 2] = vv.z; s[c][w0 + 3] = vv.w;
    }
    __syncthreads();

    int w = tid & 63, c0 = (tid >> 6) * 32;
    unsigned short* dst = xh + ((size_t)nb * WW + w) * CH + c0;
    unsigned short tmp[32];
    #pragma unroll
    for (int j = 0; j < 32; ++j) tmp[j] = f2bf(s[c0 + j][w]);
    #pragma unroll
    for (int q = 0; q < 4; ++q)
        *(bf16x8*)(dst + q * 8) = *(const bf16x8*)(tmp + q * 8);
}

// ---------------------------------------------------------------------------
// Offset conv via MFMA implicit GEMM (unchanged from round 5).
// ---------------------------------------------------------------------------
__global__ __launch_bounds__(256) void off_conv_mfma_kernel(
    const unsigned short* __restrict__ xh,   // (B,64,64,128) bf16
    const unsigned short* __restrict__ wpo,  // packed A frags
    const float* __restrict__ bias,          // (18)
    unsigned short* __restrict__ offh)       // (B,18,64,64) bf16
{
    int wgid = blockIdx.x;                   // 512
    int blk  = (wgid & 7) * 64 + (wgid >> 3);
    int b = blk >> 6, oh = blk & 63;
    int tid = threadIdx.x;
    int lane = tid & 63;
    int nt = tid >> 6;
    int nl = lane & 15;
    int kg = lane >> 4;

    f32x4 acc0 = {0.f, 0.f, 0.f, 0.f}, acc1 = {0.f, 0.f, 0.f, 0.f};
    const unsigned short* xb = xh + (size_t)b * HH * WW * CH;

    for (int k = 0; k < 9; ++k) {
        int ky = k / 3, kx = k - ky * 3;
        int ih = oh - 1 + ky;
        if (ih < 0 || ih >= HH) continue;
        int iw = nt * 16 + nl + kx - 1;
        bool valid = (iw >= 0) && (iw < WW);
        const unsigned short* row = xb + ((size_t)ih * WW + (valid ? iw : 0)) * CH + kg * 8;
        const unsigned short* wk = wpo + (size_t)k * 4096;
        #pragma unroll
        for (int kk = 0; kk < 4; ++kk) {
            bf16x8 bfrag = {0, 0, 0, 0, 0, 0, 0, 0};
            if (valid) bfrag = *(const bf16x8*)(row + kk * 32);
            bf16x8 a0 = *(const bf16x8*)(wk + (kk * 2 + 0) * 512 + lane * 8);
            bf16x8 a1 = *(const bf16x8*)(wk + (kk * 2 + 1) * 512 + lane * 8);
            acc0 = __builtin_amdgcn_mfma_f32_16x16x32_bf16(a0, bfrag, acc0, 0, 0, 0);
            acc1 = __builtin_amdgcn_mfma_f32_16x16x32_bf16(a1, bfrag, acc1, 0, 0, 0);
        }
    }

    int ow = nt * 16 + nl;
    #pragma unroll
    for (int r = 0; r < 4; ++r) {
        int co = kg * 4 + r;                 // M-tile 0: co 0..15
        offh[(((size_t)b * OFFC + co) * HH + oh) * WW + ow] = f2bf(acc0[r] + bias[co]);
    }
    if (kg == 0) {
        #pragma unroll
        for (int r = 0; r < 2; ++r) {
            int co = 16 + r;                 // M-tile 1: co 16,17
            offh[(((size_t)b * OFFC + co) * HH + oh) * WW + ow] = f2bf(acc1[r] + bias[co]);
        }
    }
}

// ---------------------------------------------------------------------------
// Deformable conv (K=3, s1, pad 2, dil 2) via bf16 MFMA, NHWC input.
// Pipelined with REGISTER A-prefetch: per tap k we issue gathers(k+1) then
// A-frag loads(k+1); MFMA(k) consumes A(k) (already resident — its vmcnt was
// retired by blend(k)'s wait last iteration) + ds_reads only, so the
// in-flight gathers are never drained by the MFMA phase.
// ---------------------------------------------------------------------------
#define DEF_COORD(K) do {                                                     \
    int ky = (K) / 3, kx = (K) - ky * 3;                                      \
    float ys = (float)(oh - 2 + ky * 2) + dyv[K];                             \
    float xs = (float)(ow_g - 2 + kx * 2) + dxv[K];                           \
    float y0f = floorf(ys), x0f = floorf(xs);                                 \
    float fy = ys - y0f, fx = xs - x0f;                                       \
    int y0 = (int)y0f, x0i = (int)x0f;                                        \
    int y1 = y0 + 1, x1 = x0i + 1;                                            \
    bool vy0 = (y0 >= 0) & (y0 < HH), vy1 = (y1 >= 0) & (y1 < HH);            \
    bool vx0 = (x0i >= 0) & (x0i < WW), vx1 = (x1 >= 0) & (x1 < WW);          \
    int y0c = min(max(y0, 0), HH - 1), y1c = min(max(y1, 0), HH - 1);         \
    int x0c = min(max(x0i, 0), WW - 1), x1c = min(max(x1, 0), WW - 1);        \
    cw0 = (1.f - fy) * (1.f - fx) * ((vy0 && vx0) ? 1.f : 0.f);               \
    cw1 = (1.f - fy) * fx         * ((vy0 && vx1) ? 1.f : 0.f);               \
    cw2 = fy * (1.f - fx)         * ((vy1 && vx0) ? 1.f : 0.f);               \
    cw3 = fy * fx                 * ((vy1 && vx1) ? 1.f : 0.f);               \
    p0 = xb + ((size_t)(y0c * WW + x0c)) * CH + ci0;                          \
    p1 = xb + ((size_t)(y0c * WW + x1c)) * CH + ci0;                          \
    p2 = xb + ((size_t)(y1c * WW + x0c)) * CH + ci0;                          \
    p3 = xb + ((size_t)(y1c * WW + x1c)) * CH + ci0;                          \
} while (0)

#define DEF_GATHER() do {                                                     \
    s0a = *(const bf16x8*)(p0); s0b = *(const bf16x8*)(p0 + 8);               \
    s1a = *(const bf16x8*)(p1); s1b = *(const bf16x8*)(p1 + 8);               \
    s2a = *(const bf16x8*)(p2); s2b = *(const bf16x8*)(p2 + 8);               \
    s3a = *(const bf16x8*)(p3); s3b = *(const bf16x8*)(p3 + 8);               \
} while (0)

#define DEF_ALOADS(K, ARR) do {                                               \
    const unsigned short* wk_ = wpk + (size_t)(K) * 16384;                    \
    _Pragma("unroll")                                                         \
    for (int kk = 0; kk < 4; ++kk) {                                          \
        ARR[kk * 2 + 0] = *(const bf16x8*)(wk_ + (kk * 8 + 2 * wv)     * 512 + lane * 8); \
        ARR[kk * 2 + 1] = *(const bf16x8*)(wk_ + (kk * 8 + 2 * wv + 1) * 512 + lane * 8); \
    }                                                                         \
} while (0)

#define DEF_BLEND_WRITE() do {                                                \
    union { bf16x8 v8; unsigned short u[8]; } w0u, w1u;                       \
    _Pragma("unroll")                                                         \
    for (int j = 0; j < 8; ++j) {                                             \
        float a0 = cw0 * bf2f((unsigned short)s0a[j])                         \
                 + cw1 * bf2f((unsigned short)s1a[j])                         \
                 + cw2 * bf2f((unsigned short)s2a[j])                         \
                 + cw3 * bf2f((unsigned short)s3a[j]);                        \
        float a1 = cw0 * bf2f((unsigned short)s0b[j])                         \
                 + cw1 * bf2f((unsigned short)s1b[j])                         \
                 + cw2 * bf2f((unsigned short)s2b[j])                         \
                 + cw3 * bf2f((unsigned short)s3b[j]);                        \
        w0u.u[j] = f2bf(a0); w1u.u[j] = f2bf(a1);                             \
    }                                                                         \
    int base_ = s_ow * 256 + ci0 * 2;                                         \
    int swz_  = (s_ow & 7) << 4;                                              \
    *(bf16x8*)((char*)sB + ( base_        ^ swz_)) = w0u.v8;                  \
    *(bf16x8*)((char*)sB + ((base_ + 16)  ^ swz_)) = w1u.v8;                  \
} while (0)

#define DEF_MFMA(ARR) do {                                                    \
    _Pragma("unroll")                                                         \
    for (int kk = 0; kk < 4; ++kk) {                                          \
        _Pragma("unroll")                                                     \
        for (int owt = 0; owt < 2; ++owt) {                                   \
            int owl = owt * 16 + (lane & 15);                                 \
            int rbyte = (owl * 256 + (kk * 32 + (lane >> 4) * 8) * 2)         \
                        ^ ((owl & 7) << 4);                                   \
            bf16x8 bfv = *(const bf16x8*)((const char*)sB + rbyte);           \
            acc[0][owt] = __builtin_amdgcn_mfma_f32_16x16x32_bf16(            \
                              ARR[kk * 2 + 0], bfv, acc[0][owt], 0, 0, 0);    \
            acc[1][owt] = __builtin_amdgcn_mfma_f32_16x16x32_bf16(            \
                              ARR[kk * 2 + 1], bfv, acc[1][owt], 0, 0, 0);    \
        }                                                                     \
    }                                                                         \
} while (0)

// one pipeline step: prefetch tap KN (gathers then A->ARRN), run MFMA on ARRC
#define DEF_STEP(KN, ARRN, ARRC) do {                                         \
    DEF_COORD(KN); DEF_GATHER(); DEF_ALOADS(KN, ARRN);                        \
    DEF_MFMA(ARRC);                                                           \
    __syncthreads();                                                          \
    DEF_BLEND_WRITE();                                                        \
    __syncthreads();                                                          \
} while (0)

__global__ __launch_bounds__(256, 2) void deform_mfma2_kernel(
    const unsigned short* __restrict__ xh,    // (B,64,64,128) bf16 (sampled)
    const unsigned short* __restrict__ offh,  // (B,18,64,64) bf16
    const unsigned short* __restrict__ wpk,   // packed A frags
    const float* __restrict__ g, const float* __restrict__ beta,
    const float* __restrict__ m, const float* __restrict__ v,
    const float* __restrict__ residual,       // layer2 only
    unsigned short* __restrict__ out_h,       // layer1: NHWC bf16 out
    float* __restrict__ out_f)                // layer2: NCHW f32 out
{
    __shared__ unsigned short sB[32 * 128];   // 8 KB [ow][ci], swizzled

    int wgid = blockIdx.x;                    // 1024
    int blk  = (wgid & 7) * 128 + (wgid >> 3);
    int owh = blk & 1, oh = (blk >> 1) & 63, b = blk >> 7;
    int ow0 = owh * 32;
    int tid = threadIdx.x, lane = tid & 63, wv = tid >> 6;

    int s_ow = tid >> 3;                      // 0..31
    int ci0  = (tid & 7) * 16;
    int ow_g = ow0 + s_ow;

    const unsigned short* xb = xh + (size_t)b * HH * WW * CH;

    // preload all 9 taps' offsets (independent scalar loads, one-time)
    float dyv[9], dxv[9];
    #pragma unroll
    for (int k = 0; k < 9; ++k) {
        dyv[k] = bf2f(offh[(((size_t)b * OFFC + 2 * k)     * HH + oh) * WW + ow_g]);
        dxv[k] = bf2f(offh[(((size_t)b * OFFC + 2 * k + 1) * HH + oh) * WW + ow_g]);
    }

    f32x4 acc[2][2];
    #pragma unroll
    for (int a = 0; a < 2; ++a)
        #pragma unroll
        for (int q = 0; q < 2; ++q) acc[a][q] = (f32x4){0.f, 0.f, 0.f, 0.f};

    float cw0, cw1, cw2, cw3;
    const unsigned short *p0, *p1, *p2, *p3;
    bf16x8 s0a, s0b, s1a, s1b, s2a, s2b, s3a, s3b;
    bf16x8 aA[8], aB[8];

    // prologue: gathers(0) then A(0) -> aA; blend waits gathers (A drains too,
    // harmless: A(0) needed right after the barrier anyway)
    DEF_COORD(0); DEF_GATHER(); DEF_ALOADS(0, aA);
    DEF_BLEND_WRITE();
    __syncthreads();

    DEF_STEP(1, aB, aA);   // k=0
    DEF_STEP(2, aA, aB);   // k=1
    DEF_STEP(3, aB, aA);   // k=2
    DEF_STEP(4, aA, aB);   // k=3
    DEF_STEP(5, aB, aA);   // k=4
    DEF_STEP(6, aA, aB);   // k=5
    DEF_STEP(7, aB, aA);   // k=6
    DEF_STEP(8, aA, aB);   // k=7
    DEF_MFMA(aA);          // k=8 (no prefetch, no trailing barrier)

    // ---- epilogue ------------------------------------------------------
    if (out_h != nullptr) {
        // layer 1: BN + ReLU -> NHWC bf16
        #pragma unroll
        for (int otl = 0; otl < 2; ++otl) {
            int ob = (2 * wv + otl) * 16 + (lane >> 4) * 4;
            float inv[4], sh[4];
            #pragma unroll
            for (int r = 0; r < 4; ++r) {
                int o = ob + r;
                float iv = g[o] / sqrtf(v[o] + 1e-5f);
                inv[r] = iv; sh[r] = beta[o] - m[o] * iv;
            }
            #pragma unroll
            for (int owt = 0; owt < 2; ++owt) {
                int ow = ow0 + owt * 16 + (lane & 15);
                union { bf16x4 v4; unsigned short u[4]; } pk;
                #pragma unroll
                for (int r = 0; r < 4; ++r) {
                    float val = acc[otl][owt][r] * inv[r] + sh[r];
                    pk.u[r] = f2bf(fmaxf(val, 0.f));
                }
                *(bf16x4*)(out_h + ((size_t)(b * HH + oh) * WW + ow) * CH + ob) = pk.v4;
            }
        }
    } else {
        // layer 2: BN + residual + ReLU -> NCHW f32
        #pragma unroll
        for (int otl = 0; otl < 2; ++otl) {
            #pragma unroll
            for (int r = 0; r < 4; ++r) {
                int o = (2 * wv + otl) * 16 + (lane >> 4) * 4 + r;
                float iv = g[o] / sqrtf(v[o] + 1e-5f);
                float sh = beta[o] - m[o] * iv;
                #pragma unroll
                for (int owt = 0; owt < 2; ++owt) {
                    int ow = ow0 + owt * 16 + (lane & 15);
                    size_t idx = (((size_t)b * CH + o) * HH + oh) * WW + ow;
                    float val = acc[otl][owt][r] * iv + sh + residual[idx];
                    out_f[idx] = fmaxf(val, 0.f);
                }
            }
        }
    }
}

// ---------------------------------------------------------------------------
extern "C" void kernel_launch(void* const* d_in, const int* in_sizes, int n_in,
                              void* d_out, int out_size, void* d_ws, size_t ws_size,
                              hipStream_t stream)
{
    const float* x      = (const float*)d_in[0];
    const float* w_off1 = (const float*)d_in[1];
    const float* b_off1 = (const float*)d_in[2];
    const float* w_dc1  = (const float*)d_in[3];
    const float* g1     = (const float*)d_in[4];
    const float* beta1  = (const float*)d_in[5];
    const float* m1     = (const float*)d_in[6];
    const float* v1     = (const float*)d_in[7];
    const float* w_off2 = (const float*)d_in[8];
    const float* b_off2 = (const float*)d_in[9];
    const float* w_dc2  = (const float*)d_in[10];
    const float* g2     = (const float*)d_in[11];
    const float* beta2  = (const float*)d_in[12];
    const float* m2     = (const float*)d_in[13];
    const float* v2     = (const float*)d_in[14];
    float* out = (float*)d_out;

    char* ws = (char*)d_ws;
    unsigned short* xh    = (unsigned short*)ws;                  // 8,388,608 B
    unsigned short* out1h = (unsigned short*)(ws + 8388608);      // 8,388,608 B
    unsigned short* offh  = (unsigned short*)(ws + 16777216);     // 1,179,648 B
    unsigned short* wpk1  = (unsigned short*)(ws + 17956864);     //   294,912 B
    unsigned short* wpk2  = (unsigned short*)(ws + 18251776);     //   294,912 B
    unsigned short* wpo1  = (unsigned short*)(ws + 18546688);     //    73,728 B
    unsigned short* wpo2  = (unsigned short*)(ws + 18620416);     //    73,728 B
    // total 18,694,144 B

    prep_kernel<<<1952, 256, 0, stream>>>(x, xh, w_dc1, w_dc2, w_off1, w_off2,
                                          wpk1, wpk2, wpo1, wpo2);

    // Layer 1
    off_conv_mfma_kernel<<<512, 256, 0, stream>>>(xh, wpo1, b_off1, offh);
    deform_mfma2_kernel<<<1024, 256, 0, stream>>>(xh, offh, wpk1,
                                                  g1, beta1, m1, v1,
                                                  nullptr, out1h, nullptr);
    // Layer 2
    off_conv_mfma_kernel<<<512, 256, 0, stream>>>(out1h, wpo2, b_off2, offh);
    deform_mfma2_kernel<<<1024, 256, 0, stream>>>(out1h, offh, wpk2,
                                                  g2, beta2, m2, v2,
                                                  x, nullptr, out);
}